// Round 1
// baseline (2459.267 us; speedup 1.0000x reference)
//
#include <hip/hip_runtime.h>

#define D_MODEL 1024
#define NHEADS  16
#define DK      64
#define BATCH   4
#define SEQ     2048
#define MROWS   (BATCH*SEQ)      // 8192
#define BHCOUNT (BATCH*NHEADS)   // 64

// ---------------- GEMM: C = A @ W^T + bias ----------------
// A: [M,K] row-major, W: [N,K] row-major (so inner product is over contiguous K).
// MODE 0: C row-major [M,N]
// MODE 1: qkv head layout: C[((b*NHEADS+h)*SEQ + s)*DK + dk], col = h*64+dk
template<int MODE>
__global__ __launch_bounds__(256)
void gemm_nt_kernel(const float* __restrict__ A, const float* __restrict__ W,
                    const float* __restrict__ bias, float* __restrict__ C,
                    int M, int N, int K)
{
    // k-major LDS tiles; stride 68 floats keeps float4 rows 16B-aligned and
    // bank conflicts <=2-way (free on gfx950).
    __shared__ float As[16][68];
    __shared__ float Ws[16][68];
    const int tid = threadIdx.x;
    const int bm = blockIdx.y * 64;
    const int bn = blockIdx.x * 64;
    const int ty = tid >> 4;        // 0..15 -> rows 4*ty..+3
    const int tx = tid & 15;        // 0..15 -> cols 4*tx..+3
    const int lr = tid >> 2;        // 0..63 load row
    const int lq = tid & 3;         // 0..3  load k-quarter

    float acc[4][4];
    #pragma unroll
    for (int i = 0; i < 4; ++i)
        #pragma unroll
        for (int j = 0; j < 4; ++j) acc[i][j] = 0.f;

    for (int k0 = 0; k0 < K; k0 += 16) {
        __syncthreads();
        float4 a4 = *(const float4*)(A + (size_t)(bm + lr) * K + k0 + lq * 4);
        float4 w4 = *(const float4*)(W + (size_t)(bn + lr) * K + k0 + lq * 4);
        As[lq*4+0][lr] = a4.x; As[lq*4+1][lr] = a4.y;
        As[lq*4+2][lr] = a4.z; As[lq*4+3][lr] = a4.w;
        Ws[lq*4+0][lr] = w4.x; Ws[lq*4+1][lr] = w4.y;
        Ws[lq*4+2][lr] = w4.z; Ws[lq*4+3][lr] = w4.w;
        __syncthreads();
        #pragma unroll
        for (int k = 0; k < 16; ++k) {
            float4 av = *(const float4*)&As[k][ty*4];
            float4 wv = *(const float4*)&Ws[k][tx*4];
            float a_[4] = {av.x, av.y, av.z, av.w};
            float w_[4] = {wv.x, wv.y, wv.z, wv.w};
            #pragma unroll
            for (int i = 0; i < 4; ++i)
                #pragma unroll
                for (int j = 0; j < 4; ++j)
                    acc[i][j] += a_[i] * w_[j];
        }
    }

    float4 b4 = *(const float4*)(bias + bn + tx*4);
    float bb[4] = {b4.x, b4.y, b4.z, b4.w};

    if (MODE == 0) {
        #pragma unroll
        for (int i = 0; i < 4; ++i) {
            int row = bm + ty*4 + i;
            float4 o = make_float4(acc[i][0]+bb[0], acc[i][1]+bb[1],
                                   acc[i][2]+bb[2], acc[i][3]+bb[3]);
            *(float4*)(C + (size_t)row * N + bn + tx*4) = o;
        }
    } else {
        // bn is a multiple of 64 -> whole block is one head; block rows stay
        // inside one batch (SEQ % 64 == 0).
        const int h = bn >> 6;
        const int b = bm / SEQ;
        const int s0 = bm - b * SEQ;
        #pragma unroll
        for (int i = 0; i < 4; ++i) {
            int s = s0 + ty*4 + i;
            float4 o = make_float4(acc[i][0]+bb[0], acc[i][1]+bb[1],
                                   acc[i][2]+bb[2], acc[i][3]+bb[3]);
            *(float4*)(C + ((size_t)(b*NHEADS + h) * SEQ + s) * DK + tx*4) = o;
        }
    }
}

// ---------------- Flash-style fused attention (fp32) ----------------
// Grid: (SEQ/64, BHCOUNT). Block 256 threads handles 64 query rows of one
// (b,h) pair. Per 64-key tile: scores -> LDS, online softmax with per-thread
// (m,l) state, PV accumulation in registers. Each thread owns query row
// q=tid/4 and dim slice quad=tid&3 (dims 4*quad+16*u+w).
__global__ __launch_bounds__(256)
void attn_kernel(const float* __restrict__ Q, const float* __restrict__ K,
                 const float* __restrict__ V, float* __restrict__ AO)
{
    __shared__ float Qs[64][68];
    __shared__ float Ks[64][68];
    __shared__ float Vs[64][68];
    __shared__ float Ss[64][68];

    const int tid  = threadIdx.x;
    const int qblk = blockIdx.x;   // 0..31
    const int bh   = blockIdx.y;   // 0..63
    const int b = bh >> 4, h = bh & 15;
    const int q0 = qblk * 64;

    const float* Qb = Q + ((size_t)bh * SEQ + q0) * DK;
    const float* Kb = K + (size_t)bh * SEQ * DK;
    const float* Vb = V + (size_t)bh * SEQ * DK;

    const int lr = tid >> 2, lq = tid & 3;
    #pragma unroll
    for (int u = 0; u < 4; ++u) {
        int d = lq*4 + u*16;
        *(float4*)&Qs[lr][d] = *(const float4*)(Qb + lr*DK + d);
    }

    const int q    = tid >> 2;   // 0..63 query row owned by this thread
    const int quad = tid & 3;    // 0..3

    float m = -1e30f, l = 0.f;
    float O[16];
    #pragma unroll
    for (int i = 0; i < 16; ++i) O[i] = 0.f;

    for (int kt = 0; kt < SEQ/64; ++kt) {
        __syncthreads();   // previous tile's readers are done
        #pragma unroll
        for (int u = 0; u < 4; ++u) {
            int d = lq*4 + u*16;
            *(float4*)&Ks[lr][d] = *(const float4*)(Kb + (size_t)(kt*64 + lr)*DK + d);
            *(float4*)&Vs[lr][d] = *(const float4*)(Vb + (size_t)(kt*64 + lr)*DK + d);
        }
        __syncthreads();

        // Phase A: scores for row q, keys {quad, 4+quad, ..., 60+quad}
        float sc[16];
        #pragma unroll
        for (int kk = 0; kk < 16; ++kk) sc[kk] = 0.f;
        #pragma unroll
        for (int d = 0; d < 64; d += 4) {
            float4 qv = *(const float4*)&Qs[q][d];
            #pragma unroll
            for (int kk = 0; kk < 16; ++kk) {
                float4 kv = *(const float4*)&Ks[kk*4 + quad][d];
                sc[kk] += qv.x*kv.x + qv.y*kv.y + qv.z*kv.z + qv.w*kv.w;
            }
        }
        #pragma unroll
        for (int kk = 0; kk < 16; ++kk)
            Ss[q][kk*4 + quad] = sc[kk] * 0.125f;   // 1/sqrt(64)
        __syncthreads();

        // Phase B: online softmax + PV (all 4 quad-threads of row q compute
        // identical m/l — no extra sync needed)
        float tm = m;
        #pragma unroll
        for (int j = 0; j < 64; ++j) tm = fmaxf(tm, Ss[q][j]);
        float alpha = __expf(m - tm);
        m = tm;
        l *= alpha;
        #pragma unroll
        for (int i = 0; i < 16; ++i) O[i] *= alpha;
        #pragma unroll 8
        for (int j = 0; j < 64; ++j) {
            float p = __expf(Ss[q][j] - m);
            l += p;
            #pragma unroll
            for (int u = 0; u < 4; ++u) {
                float4 vv = *(const float4*)&Vs[j][quad*4 + u*16];
                O[u*4+0] += p*vv.x; O[u*4+1] += p*vv.y;
                O[u*4+2] += p*vv.z; O[u*4+3] += p*vv.w;
            }
        }
    }

    float rl = 1.f / l;
    float* aorow = AO + ((size_t)(b * SEQ + q0 + q)) * D_MODEL + h * DK;
    #pragma unroll
    for (int u = 0; u < 4; ++u) {
        float4 o = make_float4(O[u*4+0]*rl, O[u*4+1]*rl, O[u*4+2]*rl, O[u*4+3]*rl);
        *(float4*)(aorow + quad*4 + u*16) = o;
    }
}

extern "C" void kernel_launch(void* const* d_in, const int* in_sizes, int n_in,
                              void* d_out, int out_size, void* d_ws, size_t ws_size,
                              hipStream_t stream)
{
    const float* x  = (const float*)d_in[0];
    const float* wq = (const float*)d_in[1];
    const float* bq = (const float*)d_in[2];
    const float* wk = (const float*)d_in[3];
    const float* bk = (const float*)d_in[4];
    const float* wv = (const float*)d_in[5];
    const float* bv = (const float*)d_in[6];
    const float* wo = (const float*)d_in[7];
    const float* bo = (const float*)d_in[8];
    float* out = (float*)d_out;

    const size_t qkv_elems = (size_t)BHCOUNT * SEQ * DK;  // 8,388,608 floats
    float* Qb = (float*)d_ws;
    float* Kb = Qb + qkv_elems;
    float* Vb = Kb + qkv_elems;
    float* AO = Vb + qkv_elems;   // merged [B,S,D_MODEL]
    // total ws use: 4 * 32 MiB = 128 MiB

    dim3 ggrid(D_MODEL/64, MROWS/64);   // (16,128)
    gemm_nt_kernel<1><<<ggrid, 256, 0, stream>>>(x, wq, bq, Qb, MROWS, D_MODEL, D_MODEL);
    gemm_nt_kernel<1><<<ggrid, 256, 0, stream>>>(x, wk, bk, Kb, MROWS, D_MODEL, D_MODEL);
    gemm_nt_kernel<1><<<ggrid, 256, 0, stream>>>(x, wv, bv, Vb, MROWS, D_MODEL, D_MODEL);

    dim3 agrid(SEQ/64, BHCOUNT);        // (32,64)
    attn_kernel<<<agrid, 256, 0, stream>>>(Qb, Kb, Vb, AO);

    gemm_nt_kernel<0><<<ggrid, 256, 0, stream>>>(AO, wo, bo, out, MROWS, D_MODEL, D_MODEL);
}

// Round 2
// 546.974 us; speedup vs baseline: 4.4961x; 4.4961x over previous
//
#include <hip/hip_runtime.h>

#define D_MODEL 1024
#define NHEADS  16
#define DK      64
#define BATCH   4
#define SEQ     2048
#define MROWS   (BATCH*SEQ)      // 8192
#define BHCOUNT (BATCH*NHEADS)   // 64

typedef _Float16 half8 __attribute__((ext_vector_type(8)));
typedef _Float16 half4 __attribute__((ext_vector_type(4)));
typedef float    floatx4 __attribute__((ext_vector_type(4)));

// ---------------- fp32 -> fp16 conversion ----------------
__global__ __launch_bounds__(256)
void cvt_f32_f16(const float* __restrict__ in, _Float16* __restrict__ out) {
    size_t i = ((size_t)blockIdx.x*256 + threadIdx.x)*4;
    float4 v = *(const float4*)(in + i);
    half4 h = {(_Float16)v.x, (_Float16)v.y, (_Float16)v.z, (_Float16)v.w};
    *(half4*)(out + i) = h;
}

__global__ __launch_bounds__(256)
void cvt4_f32_f16(const float* __restrict__ a, const float* __restrict__ b,
                  const float* __restrict__ c, const float* __restrict__ d,
                  _Float16* __restrict__ oa, _Float16* __restrict__ ob,
                  _Float16* __restrict__ oc, _Float16* __restrict__ od) {
    const float* src; _Float16* dst;
    switch (blockIdx.y) {
        case 0:  src=a; dst=oa; break;
        case 1:  src=b; dst=ob; break;
        case 2:  src=c; dst=oc; break;
        default: src=d; dst=od; break;
    }
    size_t i = ((size_t)blockIdx.x*256 + threadIdx.x)*4;
    float4 v = *(const float4*)(src + i);
    half4 h = {(_Float16)v.x, (_Float16)v.y, (_Float16)v.z, (_Float16)v.w};
    *(half4*)(dst + i) = h;
}

// ---------------- f16 MFMA GEMM: C = A @ W^T + bias ----------------
// A:[M,1024] f16 row-major, W:[1024,1024] f16 row-major (N,K), bias fp32.
// 128x128 tile, BK=32, 4 waves in 2x2, mfma_f32_16x16x32_f16.
// MODE 0: fp32 row-major out. MODE 1: f16 head layout [bh][s][dk].
template<int MODE>
__global__ __launch_bounds__(256)
void gemm_nt_f16(const _Float16* __restrict__ A, const _Float16* __restrict__ W,
                 const float* __restrict__ bias, void* __restrict__ Cout)
{
    __shared__ _Float16 As[128*32];   // [row][k] 8 KB
    __shared__ _Float16 Ws[128*32];
    const int t = threadIdx.x;
    const int w = t >> 6, l = t & 63;
    const int wm = w >> 1, wn = w & 1;
    const int bm = blockIdx.y*128, bn = blockIdx.x*128;
    const int lrow = l & 15, lk = (l >> 4)*8;
    const int sr = t >> 2, scc = (t & 3)*8;   // staging: row=i*64+sr, col=scc

    floatx4 acc[4][4];
    #pragma unroll
    for (int i = 0; i < 4; ++i)
        #pragma unroll
        for (int j = 0; j < 4; ++j) acc[i][j] = (floatx4){0.f,0.f,0.f,0.f};

    for (int k0 = 0; k0 < 1024; k0 += 32) {
        __syncthreads();
        #pragma unroll
        for (int i = 0; i < 2; ++i) {
            int row = i*64 + sr;
            *(float4*)&As[row*32 + scc] = *(const float4*)(A + (size_t)(bm+row)*1024 + k0 + scc);
            *(float4*)&Ws[row*32 + scc] = *(const float4*)(W + (size_t)(bn+row)*1024 + k0 + scc);
        }
        __syncthreads();
        half8 af[4], bf[4];
        #pragma unroll
        for (int i = 0; i < 4; ++i) af[i] = *(half8*)&As[(wm*64 + i*16 + lrow)*32 + lk];
        #pragma unroll
        for (int j = 0; j < 4; ++j) bf[j] = *(half8*)&Ws[(wn*64 + j*16 + lrow)*32 + lk];
        #pragma unroll
        for (int i = 0; i < 4; ++i)
            #pragma unroll
            for (int j = 0; j < 4; ++j)
                acc[i][j] = __builtin_amdgcn_mfma_f32_16x16x32_f16(af[i], bf[j], acc[i][j], 0, 0, 0);
    }

    // C/D layout: col = lane&15, row = (lane>>4)*4 + r  (verified m89/m91)
    #pragma unroll
    for (int j = 0; j < 4; ++j) {
        int gcol = bn + wn*64 + j*16 + lrow;
        float bv = bias[gcol];
        #pragma unroll
        for (int i = 0; i < 4; ++i) {
            #pragma unroll
            for (int r = 0; r < 4; ++r) {
                int gm = bm + wm*64 + i*16 + (l >> 4)*4 + r;
                float val = acc[i][j][r] + bv;
                if (MODE == 0) {
                    ((float*)Cout)[(size_t)gm*1024 + gcol] = val;
                } else {
                    int b = gm >> 11, s = gm & 2047;
                    int h = gcol >> 6, dk = gcol & 63;
                    ((_Float16*)Cout)[(((size_t)(b*NHEADS + h))*SEQ + s)*DK + dk] = (_Float16)val;
                }
            }
        }
    }
}

// ---------------- V transpose: [bh][s][dk] -> [bh][dk][s] ----------------
// Packed-u32 LDS (2 s-values per word), stride 33 -> 2-way conflicts max.
__global__ __launch_bounds__(256)
void transpose_v(const _Float16* __restrict__ V, _Float16* __restrict__ Vt)
{
    __shared__ unsigned Lt[64][33];
    const int t = threadIdx.x;
    const int bh = blockIdx.y;
    const int s0 = blockIdx.x*64;
    const _Float16* Vb = V + ((size_t)bh*SEQ + s0)*DK;
    const int sp = t >> 3, dkc = (t & 7)*8;
    uint4 r0 = *(const uint4*)(Vb + (2*sp+0)*64 + dkc);
    uint4 r1 = *(const uint4*)(Vb + (2*sp+1)*64 + dkc);
    unsigned a0[4] = {r0.x, r0.y, r0.z, r0.w};
    unsigned a1[4] = {r1.x, r1.y, r1.z, r1.w};
    #pragma unroll
    for (int i = 0; i < 4; ++i) {
        Lt[dkc+2*i+0][sp] = (a0[i] & 0xFFFFu) | (a1[i] << 16);
        Lt[dkc+2*i+1][sp] = (a0[i] >> 16)     | (a1[i] & 0xFFFF0000u);
    }
    __syncthreads();
    const int dk = t >> 2, spc = (t & 3)*8;
    uint4 o0 = {Lt[dk][spc+0], Lt[dk][spc+1], Lt[dk][spc+2], Lt[dk][spc+3]};
    uint4 o1 = {Lt[dk][spc+4], Lt[dk][spc+5], Lt[dk][spc+6], Lt[dk][spc+7]};
    _Float16* dst = Vt + ((size_t)bh*DK + dk)*SEQ + s0 + spc*2;
    *(uint4*)(dst)     = o0;
    *(uint4*)(dst + 8) = o1;
}

// ---------------- Flash attention, f16 MFMA ----------------
// Block: 64 q-rows of one bh; 4 waves x 16 q-rows. Per 64-key tile:
// QK^T (MFMA) -> online softmax on C-layout (shfl over 16-lane col groups)
// -> P via per-wave LDS into A-layout (m120 transform) -> PV (MFMA, Vt rows).
__global__ __launch_bounds__(256)
void attn_mfma(const _Float16* __restrict__ Q, const _Float16* __restrict__ K,
               const _Float16* __restrict__ Vt, _Float16* __restrict__ AO)
{
    __shared__ _Float16 Qs[64*64];    // [q][dk]
    __shared__ _Float16 Ks[64*64];    // [key][dk]
    __shared__ _Float16 Vs[64*64];    // [dk][key]  (from Vt)
    __shared__ float    Ps[4][16*65]; // per-wave P, stride 65 (~2-way banks)

    const int t = threadIdx.x;
    const int w = t >> 6, l = t & 63;
    const int lrow = l & 15, lq4 = l >> 4;
    const int bh = blockIdx.y;
    const int q0 = blockIdx.x*64;

    const _Float16* Qb = Q  + ((size_t)bh*SEQ + q0)*DK;
    const _Float16* Kb = K  + (size_t)bh*SEQ*DK;
    const _Float16* Vb = Vt + (size_t)bh*DK*SEQ;

    const int sr = t >> 3, sc8 = (t & 7)*8;  // staging: row=i*32+sr, col=sc8
    #pragma unroll
    for (int i = 0; i < 2; ++i) {
        int row = i*32 + sr;
        *(float4*)&Qs[row*64 + sc8] = *(const float4*)(Qb + row*64 + sc8);
    }

    floatx4 Oacc[4];
    #pragma unroll
    for (int n = 0; n < 4; ++n) Oacc[n] = (floatx4){0.f,0.f,0.f,0.f};
    float m_run[4], l_run[4];
    #pragma unroll
    for (int r = 0; r < 4; ++r) { m_run[r] = -1e30f; l_run[r] = 0.f; }

    for (int kt = 0; kt < SEQ/64; ++kt) {
        __syncthreads();
        #pragma unroll
        for (int i = 0; i < 2; ++i) {
            int row = i*32 + sr;
            *(float4*)&Ks[row*64 + sc8] = *(const float4*)(Kb + ((size_t)(kt*64 + row))*DK + sc8);
            *(float4*)&Vs[row*64 + sc8] = *(const float4*)(Vb + (size_t)row*SEQ + kt*64 + sc8);
        }
        __syncthreads();

        // ---- QK^T: wave w owns q rows w*16..w*16+15
        half8 qf[2];
        #pragma unroll
        for (int ks = 0; ks < 2; ++ks)
            qf[ks] = *(half8*)&Qs[(w*16 + lrow)*64 + ks*32 + lq4*8];
        floatx4 sc[4];
        #pragma unroll
        for (int j = 0; j < 4; ++j) sc[j] = (floatx4){0.f,0.f,0.f,0.f};
        #pragma unroll
        for (int j = 0; j < 4; ++j)
            #pragma unroll
            for (int ks = 0; ks < 2; ++ks) {
                half8 kf = *(half8*)&Ks[(j*16 + lrow)*64 + ks*32 + lq4*8];
                sc[j] = __builtin_amdgcn_mfma_f32_16x16x32_f16(qf[ks], kf, sc[j], 0, 0, 0);
            }

        // ---- online softmax (scale 1/sqrt(64)=0.125)
        float mnew[4], alpha[4], psum[4];
        #pragma unroll
        for (int r = 0; r < 4; ++r) {
            float mx = m_run[r];
            #pragma unroll
            for (int j = 0; j < 4; ++j) mx = fmaxf(mx, sc[j][r]*0.125f);
            #pragma unroll
            for (int msk = 1; msk <= 8; msk <<= 1) mx = fmaxf(mx, __shfl_xor(mx, msk, 64));
            mnew[r] = mx;
            alpha[r] = __expf(m_run[r] - mx);
            m_run[r] = mx;
            psum[r] = 0.f;
        }
        #pragma unroll
        for (int n = 0; n < 4; ++n)
            #pragma unroll
            for (int r = 0; r < 4; ++r) Oacc[n][r] *= alpha[r];
        #pragma unroll
        for (int j = 0; j < 4; ++j)
            #pragma unroll
            for (int r = 0; r < 4; ++r) {
                float p = __expf(sc[j][r]*0.125f - mnew[r]);
                psum[r] += p;
                Ps[w][(lq4*4 + r)*65 + j*16 + lrow] = p;   // [q][key]
            }
        #pragma unroll
        for (int r = 0; r < 4; ++r) {
            float s = psum[r];
            #pragma unroll
            for (int msk = 1; msk <= 8; msk <<= 1) s += __shfl_xor(s, msk, 64);
            l_run[r] = l_run[r]*alpha[r] + s;
        }

        // ---- PV: A-frag = P[q=lane&15][key=quad*8+j] from wave-private LDS
        #pragma unroll
        for (int ks = 0; ks < 2; ++ks) {
            const float* pr = &Ps[w][lrow*65 + ks*32 + lq4*8];
            half8 pf;
            #pragma unroll
            for (int u = 0; u < 8; ++u) pf[u] = (_Float16)pr[u];
            #pragma unroll
            for (int n = 0; n < 4; ++n) {
                half8 vf = *(half8*)&Vs[(n*16 + lrow)*64 + ks*32 + lq4*8];
                Oacc[n] = __builtin_amdgcn_mfma_f32_16x16x32_f16(pf, vf, Oacc[n], 0, 0, 0);
            }
        }
    }

    const int b = bh >> 4, h = bh & 15;
    #pragma unroll
    for (int r = 0; r < 4; ++r) {
        float inv = 1.f / l_run[r];
        int gq = q0 + w*16 + lq4*4 + r;
        _Float16* dst = AO + ((size_t)(b*SEQ + gq))*D_MODEL + h*DK;
        #pragma unroll
        for (int n = 0; n < 4; ++n)
            dst[n*16 + lrow] = (_Float16)(Oacc[n][r]*inv);
    }
}

extern "C" void kernel_launch(void* const* d_in, const int* in_sizes, int n_in,
                              void* d_out, int out_size, void* d_ws, size_t ws_size,
                              hipStream_t stream)
{
    const float* x  = (const float*)d_in[0];
    const float* wq = (const float*)d_in[1];
    const float* bq = (const float*)d_in[2];
    const float* wk = (const float*)d_in[3];
    const float* bk = (const float*)d_in[4];
    const float* wv = (const float*)d_in[5];
    const float* bv = (const float*)d_in[6];
    const float* wo = (const float*)d_in[7];
    const float* bo = (const float*)d_in[8];

    const size_t NX = (size_t)MROWS * D_MODEL;      // 8,388,608
    const size_t NW = (size_t)D_MODEL * D_MODEL;    // 1,048,576
    _Float16* xh  = (_Float16*)d_ws;
    _Float16* wqh = xh  + NX;
    _Float16* wkh = wqh + NW;
    _Float16* wvh = wkh + NW;
    _Float16* woh = wvh + NW;
    _Float16* Qh  = woh + NW;
    _Float16* Kh  = Qh  + NX;
    _Float16* Vh  = Kh  + NX;
    _Float16* Vth = Vh  + NX;
    _Float16* AOh = Vth + NX;   // total ~109 MB of d_ws

    cvt_f32_f16<<<NX/1024, 256, 0, stream>>>(x, xh);
    cvt4_f32_f16<<<dim3(NW/1024, 4), 256, 0, stream>>>(wq, wk, wv, wo, wqh, wkh, wvh, woh);

    dim3 pgrid(D_MODEL/128, MROWS/128);   // (8, 64)
    gemm_nt_f16<1><<<pgrid, 256, 0, stream>>>(xh, wqh, bq, Qh);
    gemm_nt_f16<1><<<pgrid, 256, 0, stream>>>(xh, wkh, bk, Kh);
    gemm_nt_f16<1><<<pgrid, 256, 0, stream>>>(xh, wvh, bv, Vh);

    transpose_v<<<dim3(SEQ/64, BHCOUNT), 256, 0, stream>>>(Vh, Vth);
    attn_mfma<<<dim3(SEQ/64, BHCOUNT), 256, 0, stream>>>(Qh, Kh, Vth, AOh);

    gemm_nt_f16<0><<<pgrid, 256, 0, stream>>>(AOh, woh, bo, d_out);
}

// Round 3
// 463.860 us; speedup vs baseline: 5.3017x; 1.1792x over previous
//
#include <hip/hip_runtime.h>

#define D_MODEL 1024
#define NHEADS  16
#define DK      64
#define BATCH   4
#define SEQ     2048
#define MROWS   (BATCH*SEQ)      // 8192
#define BHCOUNT (BATCH*NHEADS)   // 64

typedef _Float16 half8 __attribute__((ext_vector_type(8)));
typedef _Float16 half4 __attribute__((ext_vector_type(4)));
typedef float    floatx4 __attribute__((ext_vector_type(4)));

// async global->LDS, 16B per lane; lds dst is wave-uniform base + lane*16
__device__ __forceinline__ void load_lds16(const void* g, void* l) {
    __builtin_amdgcn_global_load_lds((const __attribute__((address_space(1))) void*)g,
                                     (__attribute__((address_space(3))) void*)l, 16, 0, 0);
}

// ---------------- fp32 -> fp16 conversion ----------------
__global__ __launch_bounds__(256)
void cvt_f32_f16(const float* __restrict__ in, _Float16* __restrict__ out) {
    size_t i = ((size_t)blockIdx.x*256 + threadIdx.x)*4;
    float4 v = *(const float4*)(in + i);
    half4 h = {(_Float16)v.x, (_Float16)v.y, (_Float16)v.z, (_Float16)v.w};
    *(half4*)(out + i) = h;
}

__global__ __launch_bounds__(256)
void cvt4_f32_f16(const float* __restrict__ a, const float* __restrict__ b,
                  const float* __restrict__ c, const float* __restrict__ d,
                  _Float16* __restrict__ oa, _Float16* __restrict__ ob,
                  _Float16* __restrict__ oc, _Float16* __restrict__ od) {
    const float* src; _Float16* dst;
    switch (blockIdx.y) {
        case 0:  src=a; dst=oa; break;
        case 1:  src=b; dst=ob; break;
        case 2:  src=c; dst=oc; break;
        default: src=d; dst=od; break;
    }
    size_t i = ((size_t)blockIdx.x*256 + threadIdx.x)*4;
    float4 v = *(const float4*)(src + i);
    half4 h = {(_Float16)v.x, (_Float16)v.y, (_Float16)v.z, (_Float16)v.w};
    *(half4*)(dst + i) = h;
}

// ---------------- f16 MFMA GEMM: C = A @ W^T + bias ----------------
// 128x128 tile, BK=32, 4 waves 2x2, mfma_f32_16x16x32_f16.
// LDS tiles row-major [row][32 halves], 16B chunks XOR-swizzled by
// chunk ^= (row>>1)&3 -> frag ds_read_b128 is 2-way (free); staging via
// global_load_lds width 16 (each lane loads the element for ITS slot).
// MODE 0: fp32 row-major out. MODE 1: f16 head layout [bh][s][dk].
template<int MODE>
__global__ __launch_bounds__(256)
void gemm_nt_f16(const _Float16* __restrict__ A, const _Float16* __restrict__ W,
                 const float* __restrict__ bias, void* __restrict__ Cout)
{
    __shared__ _Float16 As[128*32];   // 8 KB each
    __shared__ _Float16 Ws[128*32];
    const int t = threadIdx.x;
    const int w = t >> 6, l = t & 63;
    const int wm = w >> 1, wn = w & 1;
    const int bm = blockIdx.y*128, bn = blockIdx.x*128;
    const int lrow = l & 15, lq4 = l >> 4;
    // frag-read swizzled chunk offset: (row>>1)&3 == (lrow>>1)&3 (row base %16==0)
    const int xc = (lq4 ^ ((lrow >> 1) & 3)) * 8;

    // staging slots: tile = 8 chunks-of-1KB; wave w owns chunks w and 4+w.
    int srow[2], scol[2];
    #pragma unroll
    for (int it = 0; it < 2; ++it) {
        int s = (it*4 + w)*64 + l;          // 16B-slot index in tile
        int r = s >> 2;                     // 4 slots per 64B row
        int lc = (s & 3) ^ ((r >> 1) & 3);  // logical chunk this slot holds
        srow[it] = r; scol[it] = lc*8;
    }

    floatx4 acc[4][4];
    #pragma unroll
    for (int i = 0; i < 4; ++i)
        #pragma unroll
        for (int j = 0; j < 4; ++j) acc[i][j] = (floatx4){0.f,0.f,0.f,0.f};

    for (int k0 = 0; k0 < 1024; k0 += 32) {
        __syncthreads();
        #pragma unroll
        for (int it = 0; it < 2; ++it) {
            load_lds16(A + (size_t)(bm + srow[it])*1024 + k0 + scol[it], &As[(it*4+w)*512]);
            load_lds16(W + (size_t)(bn + srow[it])*1024 + k0 + scol[it], &Ws[(it*4+w)*512]);
        }
        __syncthreads();
        half8 af[4], bf[4];
        #pragma unroll
        for (int i = 0; i < 4; ++i) af[i] = *(half8*)&As[(wm*64 + i*16 + lrow)*32 + xc];
        #pragma unroll
        for (int j = 0; j < 4; ++j) bf[j] = *(half8*)&Ws[(wn*64 + j*16 + lrow)*32 + xc];
        #pragma unroll
        for (int i = 0; i < 4; ++i)
            #pragma unroll
            for (int j = 0; j < 4; ++j)
                acc[i][j] = __builtin_amdgcn_mfma_f32_16x16x32_f16(af[i], bf[j], acc[i][j], 0, 0, 0);
    }

    // C/D layout: col = lane&15, row = (lane>>4)*4 + r
    #pragma unroll
    for (int j = 0; j < 4; ++j) {
        int gcol = bn + wn*64 + j*16 + lrow;
        float bv = bias[gcol];
        #pragma unroll
        for (int i = 0; i < 4; ++i) {
            #pragma unroll
            for (int r = 0; r < 4; ++r) {
                int gm = bm + wm*64 + i*16 + lq4*4 + r;
                float val = acc[i][j][r] + bv;
                if (MODE == 0) {
                    ((float*)Cout)[(size_t)gm*1024 + gcol] = val;
                } else {
                    int b = gm >> 11, s = gm & 2047;
                    int h = gcol >> 6, dk = gcol & 63;
                    ((_Float16*)Cout)[(((size_t)(b*NHEADS + h))*SEQ + s)*DK + dk] = (_Float16)val;
                }
            }
        }
    }
}

// ---------------- V transpose: [bh][s][dk] -> [bh][dk][s] ----------------
__global__ __launch_bounds__(256)
void transpose_v(const _Float16* __restrict__ V, _Float16* __restrict__ Vt)
{
    __shared__ unsigned Lt[64][33];
    const int t = threadIdx.x;
    const int bh = blockIdx.y;
    const int s0 = blockIdx.x*64;
    const _Float16* Vb = V + ((size_t)bh*SEQ + s0)*DK;
    const int sp = t >> 3, dkc = (t & 7)*8;
    uint4 r0 = *(const uint4*)(Vb + (2*sp+0)*64 + dkc);
    uint4 r1 = *(const uint4*)(Vb + (2*sp+1)*64 + dkc);
    unsigned a0[4] = {r0.x, r0.y, r0.z, r0.w};
    unsigned a1[4] = {r1.x, r1.y, r1.z, r1.w};
    #pragma unroll
    for (int i = 0; i < 4; ++i) {
        Lt[dkc+2*i+0][sp] = (a0[i] & 0xFFFFu) | (a1[i] << 16);
        Lt[dkc+2*i+1][sp] = (a0[i] >> 16)     | (a1[i] & 0xFFFF0000u);
    }
    __syncthreads();
    const int dk = t >> 2, spc = (t & 3)*8;
    uint4 o0 = {Lt[dk][spc+0], Lt[dk][spc+1], Lt[dk][spc+2], Lt[dk][spc+3]};
    uint4 o1 = {Lt[dk][spc+4], Lt[dk][spc+5], Lt[dk][spc+6], Lt[dk][spc+7]};
    _Float16* dst = Vt + ((size_t)bh*DK + dk)*SEQ + s0 + spc*2;
    *(uint4*)(dst)     = o0;
    *(uint4*)(dst + 8) = o1;
}

// ---------------- Flash attention, f16 MFMA ----------------
// 64 q-rows/block, 4 waves x 16 q. Tiles XOR-swizzled (chunk ^= row&7, 8
// chunks/row) -> conflict-free b128 frag reads; staging via global_load_lds.
// Q frags hoisted out of the key loop. P round-trips per-wave LDS (stride 68
// floats: 16B-aligned b128 reads, 2-way writes).
__global__ __launch_bounds__(256)
void attn_mfma(const _Float16* __restrict__ Q, const _Float16* __restrict__ K,
               const _Float16* __restrict__ Vt, _Float16* __restrict__ AO)
{
    __shared__ _Float16 Qs[64*64];    // [q][dk]     8 KB
    __shared__ _Float16 Ks[64*64];    // [key][dk]   8 KB
    __shared__ _Float16 Vs[64*64];    // [dk][key]   8 KB
    __shared__ float    Ps[4][16*68]; // per-wave P  17 KB

    const int t = threadIdx.x;
    const int w = t >> 6, l = t & 63;
    const int lrow = l & 15, lq4 = l >> 4;
    const int bh = blockIdx.y;
    const int q0 = blockIdx.x*64;

    const _Float16* Qb = Q  + ((size_t)bh*SEQ + q0)*DK;
    const _Float16* Kb = K  + (size_t)bh*SEQ*DK;
    const _Float16* Vb = Vt + (size_t)bh*DK*SEQ;

    // staging slots: 8KB tile = 8 chunks-of-1KB; wave w owns chunks w, 4+w.
    int srow[2], scol[2];
    #pragma unroll
    for (int it = 0; it < 2; ++it) {
        int s = (it*4 + w)*64 + l;
        int r = s >> 3;                 // 8 slots per 128B row
        int lc = (s & 7) ^ (r & 7);
        srow[it] = r; scol[it] = lc*8;
    }
    // frag-read swizzled offsets (row&7 == lrow&7 since row bases %16==0)
    int xk[2];
    #pragma unroll
    for (int ks = 0; ks < 2; ++ks) xk[ks] = ((ks*4 + lq4) ^ (lrow & 7))*8;

    // stage Q once
    #pragma unroll
    for (int it = 0; it < 2; ++it)
        load_lds16(Qb + (size_t)srow[it]*DK + scol[it], &Qs[(it*4+w)*512]);

    floatx4 Oacc[4];
    #pragma unroll
    for (int n = 0; n < 4; ++n) Oacc[n] = (floatx4){0.f,0.f,0.f,0.f};
    float m_run[4], l_run[4];
    #pragma unroll
    for (int r = 0; r < 4; ++r) { m_run[r] = -1e30f; l_run[r] = 0.f; }
    half8 qf[2];

    for (int kt = 0; kt < SEQ/64; ++kt) {
        __syncthreads();   // prior tile's readers done (iter0: drains Q loads)
        #pragma unroll
        for (int it = 0; it < 2; ++it) {
            load_lds16(Kb + ((size_t)(kt*64 + srow[it]))*DK + scol[it], &Ks[(it*4+w)*512]);
            load_lds16(Vb + (size_t)srow[it]*SEQ + kt*64 + scol[it],    &Vs[(it*4+w)*512]);
        }
        __syncthreads();   // K/V (and on iter0, Q) ready
        if (kt == 0) {
            #pragma unroll
            for (int ks = 0; ks < 2; ++ks)
                qf[ks] = *(half8*)&Qs[(w*16 + lrow)*64 + xk[ks]];
        }

        // ---- QK^T: wave w owns q rows w*16..+15
        floatx4 sc[4];
        #pragma unroll
        for (int j = 0; j < 4; ++j) sc[j] = (floatx4){0.f,0.f,0.f,0.f};
        #pragma unroll
        for (int j = 0; j < 4; ++j)
            #pragma unroll
            for (int ks = 0; ks < 2; ++ks) {
                half8 kf = *(half8*)&Ks[(j*16 + lrow)*64 + xk[ks]];
                sc[j] = __builtin_amdgcn_mfma_f32_16x16x32_f16(qf[ks], kf, sc[j], 0, 0, 0);
            }

        // ---- online softmax (scale 0.125)
        float mnew[4], alpha[4], psum[4];
        #pragma unroll
        for (int r = 0; r < 4; ++r) {
            float mx = m_run[r];
            #pragma unroll
            for (int j = 0; j < 4; ++j) mx = fmaxf(mx, sc[j][r]*0.125f);
            #pragma unroll
            for (int msk = 1; msk <= 8; msk <<= 1) mx = fmaxf(mx, __shfl_xor(mx, msk, 64));
            mnew[r] = mx;
            alpha[r] = __expf(m_run[r] - mx);
            m_run[r] = mx;
            psum[r] = 0.f;
        }
        #pragma unroll
        for (int n = 0; n < 4; ++n)
            #pragma unroll
            for (int r = 0; r < 4; ++r) Oacc[n][r] *= alpha[r];
        #pragma unroll
        for (int j = 0; j < 4; ++j)
            #pragma unroll
            for (int r = 0; r < 4; ++r) {
                float p = __expf(sc[j][r]*0.125f - mnew[r]);
                psum[r] += p;
                Ps[w][(lq4*4 + r)*68 + j*16 + lrow] = p;   // [q][key]
            }
        #pragma unroll
        for (int r = 0; r < 4; ++r) {
            float s = psum[r];
            #pragma unroll
            for (int msk = 1; msk <= 8; msk <<= 1) s += __shfl_xor(s, msk, 64);
            l_run[r] = l_run[r]*alpha[r] + s;
        }

        // ---- PV: A-frag = P[q=lane&15][key=lq4*8+u] via wave-private LDS
        #pragma unroll
        for (int ks = 0; ks < 2; ++ks) {
            const float* pr = &Ps[w][lrow*68 + ks*32 + lq4*8];
            half8 pf;
            #pragma unroll
            for (int u = 0; u < 8; ++u) pf[u] = (_Float16)pr[u];
            #pragma unroll
            for (int n = 0; n < 4; ++n) {
                half8 vf = *(half8*)&Vs[(n*16 + lrow)*64 + xk[ks]];
                Oacc[n] = __builtin_amdgcn_mfma_f32_16x16x32_f16(pf, vf, Oacc[n], 0, 0, 0);
            }
        }
    }

    const int b = bh >> 4, h = bh & 15;
    #pragma unroll
    for (int r = 0; r < 4; ++r) {
        float inv = 1.f / l_run[r];
        int gq = q0 + w*16 + lq4*4 + r;
        _Float16* dst = AO + ((size_t)(b*SEQ + gq))*D_MODEL + h*DK;
        #pragma unroll
        for (int n = 0; n < 4; ++n)
            dst[n*16 + lrow] = (_Float16)(Oacc[n][r]*inv);
    }
}

extern "C" void kernel_launch(void* const* d_in, const int* in_sizes, int n_in,
                              void* d_out, int out_size, void* d_ws, size_t ws_size,
                              hipStream_t stream)
{
    const float* x  = (const float*)d_in[0];
    const float* wq = (const float*)d_in[1];
    const float* bq = (const float*)d_in[2];
    const float* wk = (const float*)d_in[3];
    const float* bk = (const float*)d_in[4];
    const float* wv = (const float*)d_in[5];
    const float* bv = (const float*)d_in[6];
    const float* wo = (const float*)d_in[7];
    const float* bo = (const float*)d_in[8];

    const size_t NX = (size_t)MROWS * D_MODEL;
    const size_t NW = (size_t)D_MODEL * D_MODEL;
    _Float16* xh  = (_Float16*)d_ws;
    _Float16* wqh = xh  + NX;
    _Float16* wkh = wqh + NW;
    _Float16* wvh = wkh + NW;
    _Float16* woh = wvh + NW;
    _Float16* Qh  = woh + NW;
    _Float16* Kh  = Qh  + NX;
    _Float16* Vh  = Kh  + NX;
    _Float16* Vth = Vh  + NX;
    _Float16* AOh = Vth + NX;

    cvt_f32_f16<<<NX/1024, 256, 0, stream>>>(x, xh);
    cvt4_f32_f16<<<dim3(NW/1024, 4), 256, 0, stream>>>(wq, wk, wv, wo, wqh, wkh, wvh, woh);

    dim3 pgrid(D_MODEL/128, MROWS/128);
    gemm_nt_f16<1><<<pgrid, 256, 0, stream>>>(xh, wqh, bq, Qh);
    gemm_nt_f16<1><<<pgrid, 256, 0, stream>>>(xh, wkh, bk, Kh);
    gemm_nt_f16<1><<<pgrid, 256, 0, stream>>>(xh, wvh, bv, Vh);

    transpose_v<<<dim3(SEQ/64, BHCOUNT), 256, 0, stream>>>(Vh, Vth);
    attn_mfma<<<dim3(SEQ/64, BHCOUNT), 256, 0, stream>>>(Qh, Kh, Vth, AOh);

    gemm_nt_f16<0><<<pgrid, 256, 0, stream>>>(AOh, woh, bo, d_out);
}